// Round 1
// baseline (450.599 us; speedup 1.0000x reference)
//
#include <hip/hip_runtime.h>

#define M_TOT 37440      // B*T*N_VALID = 96*390
#define N_E   768
#define K_TOT 672        // C*PH*PW = 4*14*12
#define NV    390
#define GWID  26
#define PHh   14
#define PWw   12
#define IMW   312
#define CSTRIDE 131040   // 420*312
#define NSTRIDE 524160   // 4*420*312

typedef short bf16x8 __attribute__((ext_vector_type(8)));
typedef float f32x4  __attribute__((ext_vector_type(4)));
typedef unsigned short u16;
typedef u16 u16x4 __attribute__((ext_vector_type(4)));
typedef u16 u16x8 __attribute__((ext_vector_type(8)));

// LDS row stride: 96 data + 8 pad bf16 = 208B = 13 x 16B granules (odd -> 2-way max on b128 reads)
#define ROWB 104

static __device__ __forceinline__ u16 f2bf(float f) {
  unsigned u = __builtin_bit_cast(unsigned, f);
  u = (u + 0x7FFFu + ((u >> 16) & 1u)) >> 16;   // RNE
  return (u16)u;
}

__global__ __launch_bounds__(256) void patch_gemm(
    const float* __restrict__ x, const float* __restrict__ w,
    const float* __restrict__ bias, const int* __restrict__ valid,
    float* __restrict__ out) {
  __shared__ u16 Alds[128 * ROWB];
  __shared__ u16 Blds[128 * ROWB];

  const int tid  = threadIdx.x;
  const int lane = tid & 63;
  const int wid  = tid >> 6;
  const int wr   = wid >> 1, wc = wid & 1;       // 2x2 wave grid, each 64x64 out
  const int lrow = lane & 15, lhi = lane >> 4;

  const int m0 = blockIdx.x * 128;
  const int n0 = blockIdx.y * 128;

  // ---- per-block row decode (hoisted out of K loop) ----
  const int arow = tid & 127;        // LDS row this thread stages (A and B)
  int m = m0 + arow;
  if (m >= M_TOT) m = M_TOT - 1;     // clamp: dup gather, stores guarded
  const int nimg = m / NV;
  const int v    = m - nimg * NV;
  const int g    = valid[v];
  const int gi   = g / GWID;
  const int gj   = g - gi * GWID;
  const float* xrow = x + (size_t)nimg * NSTRIDE + (size_t)(gi * PHh) * IMW + gj * PWw;

  const int half = tid >> 7;         // 0/1: which half of the K-columns this thread stages
  const float* wrow = w + (size_t)(n0 + arow) * K_TOT;

  f32x4 acc[4][4];
  #pragma unroll
  for (int i = 0; i < 4; ++i)
    #pragma unroll
    for (int j = 0; j < 4; ++j)
      acc[i][j] = (f32x4){0.f, 0.f, 0.f, 0.f};

  // K tiled by 96 = lcm(12,32): every tile is 8 whole q-runs of 12 contiguous floats
  for (int t = 0; t < 7; ++t) {
    // ---- stage A: 128 rows x 8 runs; this thread: 4 runs of its row ----
    #pragma unroll
    for (int it = 0; it < 4; ++it) {
      const int run = half + it * 2;           // 0..7
      const int rr  = t * 8 + run;             // global run index, < 56
      const int c   = rr / PHh;
      const int p   = rr - c * PHh;
      const float* src = xrow + (size_t)c * CSTRIDE + p * IMW;
      f32x4 f0 = *(const f32x4*)(src + 0);
      f32x4 f1 = *(const f32x4*)(src + 4);
      f32x4 f2 = *(const f32x4*)(src + 8);
      u16x4 h0 = {f2bf(f0.x), f2bf(f0.y), f2bf(f0.z), f2bf(f0.w)};
      u16x4 h1 = {f2bf(f1.x), f2bf(f1.y), f2bf(f1.z), f2bf(f1.w)};
      u16x4 h2 = {f2bf(f2.x), f2bf(f2.y), f2bf(f2.z), f2bf(f2.w)};
      u16* dst = &Alds[arow * ROWB + run * 12];
      *(u16x4*)(dst + 0) = h0;
      *(u16x4*)(dst + 4) = h1;
      *(u16x4*)(dst + 8) = h2;
    }
    // ---- stage B (= W rows, contiguous): this thread: 48 floats of its row ----
    #pragma unroll
    for (int i = 0; i < 6; ++i) {
      const int col = half * 48 + i * 8;
      const float* src = wrow + t * 96 + col;
      f32x4 f0 = *(const f32x4*)(src + 0);
      f32x4 f1 = *(const f32x4*)(src + 4);
      u16x8 h = {f2bf(f0.x), f2bf(f0.y), f2bf(f0.z), f2bf(f0.w),
                 f2bf(f1.x), f2bf(f1.y), f2bf(f1.z), f2bf(f1.w)};
      *(u16x8*)&Blds[arow * ROWB + col] = h;
    }
    __syncthreads();
    // ---- MFMA: 3 K-steps of 32 ----
    #pragma unroll
    for (int kk = 0; kk < 3; ++kk) {
      bf16x8 a[4], b[4];
      #pragma unroll
      for (int i = 0; i < 4; ++i)
        a[i] = *(const bf16x8*)&Alds[(wr * 64 + i * 16 + lrow) * ROWB + kk * 32 + lhi * 8];
      #pragma unroll
      for (int j = 0; j < 4; ++j)
        b[j] = *(const bf16x8*)&Blds[(wc * 64 + j * 16 + lrow) * ROWB + kk * 32 + lhi * 8];
      #pragma unroll
      for (int i = 0; i < 4; ++i)
        #pragma unroll
        for (int j = 0; j < 4; ++j)
          acc[i][j] = __builtin_amdgcn_mfma_f32_16x16x32_bf16(a[i], b[j], acc[i][j], 0, 0, 0);
    }
    __syncthreads();
  }

  // ---- epilogue: D col = lane&15 (=e), row = (lane>>4)*4 + reg ----
  float bv[4];
  #pragma unroll
  for (int j = 0; j < 4; ++j)
    bv[j] = bias[n0 + wc * 64 + j * 16 + lrow];

  #pragma unroll
  for (int i = 0; i < 4; ++i) {
    const int mbase = m0 + wr * 64 + i * 16 + lhi * 4;
    #pragma unroll
    for (int j = 0; j < 4; ++j) {
      const int e = n0 + wc * 64 + j * 16 + lrow;
      float* op = out + (size_t)mbase * N_E + e;
      #pragma unroll
      for (int tt = 0; tt < 4; ++tt) {
        if (mbase + tt < M_TOT) op[(size_t)tt * N_E] = acc[i][j][tt] + bv[j];
      }
    }
  }
}

extern "C" void kernel_launch(void* const* d_in, const int* in_sizes, int n_in,
                              void* d_out, int out_size, void* d_ws, size_t ws_size,
                              hipStream_t stream) {
  const float* x     = (const float*)d_in[0];
  const float* w     = (const float*)d_in[1];
  const float* b     = (const float*)d_in[2];
  const int*   valid = (const int*)d_in[3];
  float* out = (float*)d_out;
  dim3 grid((M_TOT + 127) / 128, N_E / 128);   // 293 x 6
  patch_gemm<<<grid, dim3(256), 0, stream>>>(x, w, b, valid, out);
}

// Round 3
// 377.166 us; speedup vs baseline: 1.1947x; 1.1947x over previous
//
#include <hip/hip_runtime.h>

#define M_TOT 37440      // B*T*N_VALID = 96*390
#define N_E   768
#define K_TOT 672        // C*PH*PW = 4*14*12
#define NV    390
#define GWID  26
#define PHh   14
#define PWw   12
#define IMW   312
#define CSTRIDE 131040   // 420*312
#define NSTRIDE 524160   // 4*420*312

typedef short bf16x8 __attribute__((ext_vector_type(8)));
typedef float f32x4  __attribute__((ext_vector_type(4)));
typedef unsigned short u16;
typedef u16 u16x4 __attribute__((ext_vector_type(4)));
typedef u16 u16x8 __attribute__((ext_vector_type(8)));

#define A_WS_BYTES 50319360u               // 37440*672*2
#define W_WS_ELEMS 516096                  // 768*672
#define WS_NEEDED (A_WS_BYTES + W_WS_ELEMS*2)

#define NBLK_A 8190                        // 37440*56/256 runs
#define NBLK_W 252                         // 516096/(256*8)

static __device__ __forceinline__ u16 f2bf(float f) {
  unsigned u = __builtin_bit_cast(unsigned, f);
  u = (u + 0x7FFFu + ((u >> 16) & 1u)) >> 16;   // RNE
  return (u16)u;
}

#define GLOAD_LDS16(g, l) \
  __builtin_amdgcn_global_load_lds((const __attribute__((address_space(1))) void*)(g), \
                                   (__attribute__((address_space(3))) void*)(l), 16, 0, 0)

// ---------------- Kernel 1: patchify x -> bf16 A[M][672], convert W -> bf16 ----------------
__global__ __launch_bounds__(256) void patchify(
    const float* __restrict__ x, const float* __restrict__ w,
    const int* __restrict__ valid, u16* __restrict__ A, u16* __restrict__ Wb) {
  const int bid = blockIdx.x;
  const int tid = threadIdx.x;
  if (bid < NBLK_A) {
    const int g  = bid * 256 + tid;          // run id, < 2096640
    const int m  = g / 56;
    const int rr = g - m * 56;
    const int nimg = m / NV;
    const int v    = m - nimg * NV;
    const int gidx = valid[v];
    const int gi = gidx / GWID, gj = gidx - gi * GWID;
    const int c  = rr / PHh,    p  = rr - c * PHh;
    const float* src = x + (size_t)nimg * NSTRIDE + (size_t)c * CSTRIDE
                         + (size_t)(gi * PHh + p) * IMW + gj * PWw;
    f32x4 f0 = *(const f32x4*)(src + 0);
    f32x4 f1 = *(const f32x4*)(src + 4);
    f32x4 f2 = *(const f32x4*)(src + 8);
    u16* dst = A + (size_t)m * K_TOT + rr * 12;
    u16x8 h01 = {f2bf(f0.x), f2bf(f0.y), f2bf(f0.z), f2bf(f0.w),
                 f2bf(f1.x), f2bf(f1.y), f2bf(f1.z), f2bf(f1.w)};
    u16x4 h2  = {f2bf(f2.x), f2bf(f2.y), f2bf(f2.z), f2bf(f2.w)};
    *(u16x8*)(dst + 0) = h01;
    *(u16x4*)(dst + 8) = h2;
  } else {
    const int g = (bid - NBLK_A) * 256 + tid;   // float8 id, < 64512
    const float* src = w + (size_t)g * 8;
    f32x4 f0 = *(const f32x4*)(src + 0);
    f32x4 f1 = *(const f32x4*)(src + 4);
    u16x8 h = {f2bf(f0.x), f2bf(f0.y), f2bf(f0.z), f2bf(f0.w),
               f2bf(f1.x), f2bf(f1.y), f2bf(f1.z), f2bf(f1.w)};
    *(u16x8*)(Wb + (size_t)g * 8) = h;
  }
}

// ---------------- Kernel 2: dense bf16 GEMM (m97 structure, BK=96) ----------------
// C[M][768] = A[M][672] * Wb[768][672]^T + bias
__global__ __launch_bounds__(256) void gemm_bf16(
    const u16* __restrict__ A, const u16* __restrict__ Bw,
    const float* __restrict__ bias, float* __restrict__ out) {
  __shared__ u16 Alds[128 * 96];
  __shared__ u16 Blds[128 * 96];
  char* AldsB = (char*)Alds;
  char* BldsB = (char*)Blds;

  const int tid  = threadIdx.x;
  const int lane = tid & 63;
  const int wid  = tid >> 6;
  const int wr   = wid >> 1, wc = wid & 1;
  const int lrow = lane & 15, lhi = lane >> 4;

  const int n0 = blockIdx.x * 128;   // 6 n-tiles (fastest -> L3 reuse of A tile)
  const int m0 = blockIdx.y * 128;   // 293 m-tiles

  // per-lane source offsets for the 6 A-chunk + 6 B-chunk gload_lds per K-iter
  // chunk ci = wid*384 + j*64 + lane ; row = ci/12 ; 16B-col = ci%12
  int aoff[6], boff[6];
  #pragma unroll
  for (int j = 0; j < 6; ++j) {
    const int ci  = wid * 384 + j * 64 + lane;
    const int row = ci / 12;
    const int c16 = ci - row * 12;
    int ar = m0 + row; if (ar >= M_TOT) ar = M_TOT - 1;   // clamp tail
    aoff[j] = ar * K_TOT + c16 * 8;
    boff[j] = (n0 + row) * K_TOT + c16 * 8;
  }

  f32x4 acc[4][4];
  #pragma unroll
  for (int i = 0; i < 4; ++i)
    #pragma unroll
    for (int j = 0; j < 4; ++j)
      acc[i][j] = (f32x4){0.f, 0.f, 0.f, 0.f};

  for (int t = 0; t < 7; ++t) {
    const int kb = t * 96;
    #pragma unroll
    for (int j = 0; j < 6; ++j)
      GLOAD_LDS16(A + aoff[j] + kb, AldsB + (wid * 6 + j) * 1024);
    #pragma unroll
    for (int j = 0; j < 6; ++j)
      GLOAD_LDS16(Bw + boff[j] + kb, BldsB + (wid * 6 + j) * 1024);
    __syncthreads();   // drains vmcnt before any wave reads LDS

    #pragma unroll
    for (int kk = 0; kk < 3; ++kk) {
      bf16x8 a[4], b[4];
      #pragma unroll
      for (int i = 0; i < 4; ++i)
        a[i] = *(const bf16x8*)&Alds[(wr * 64 + i * 16 + lrow) * 96 + kk * 32 + lhi * 8];
      #pragma unroll
      for (int j = 0; j < 4; ++j)
        b[j] = *(const bf16x8*)&Blds[(wc * 64 + j * 16 + lrow) * 96 + kk * 32 + lhi * 8];
      #pragma unroll
      for (int i = 0; i < 4; ++i)
        #pragma unroll
        for (int j = 0; j < 4; ++j)
          acc[i][j] = __builtin_amdgcn_mfma_f32_16x16x32_bf16(a[i], b[j], acc[i][j], 0, 0, 0);
    }
    __syncthreads();
  }

  float bv[4];
  #pragma unroll
  for (int j = 0; j < 4; ++j)
    bv[j] = bias[n0 + wc * 64 + j * 16 + lrow];

  #pragma unroll
  for (int i = 0; i < 4; ++i) {
    const int mbase = m0 + wr * 64 + i * 16 + lhi * 4;
    #pragma unroll
    for (int j = 0; j < 4; ++j) {
      const int e = n0 + wc * 64 + j * 16 + lrow;
      float* op = out + (size_t)mbase * N_E + e;
      #pragma unroll
      for (int tt = 0; tt < 4; ++tt) {
        if (mbase + tt < M_TOT) op[(size_t)tt * N_E] = acc[i][j][tt] + bv[j];
      }
    }
  }
}

// ---------------- Fallback (round-1 fused kernel) if ws too small ----------------
#define ROWB 104
__global__ __launch_bounds__(256) void patch_gemm_fused(
    const float* __restrict__ x, const float* __restrict__ w,
    const float* __restrict__ bias, const int* __restrict__ valid,
    float* __restrict__ out) {
  __shared__ u16 Alds[128 * ROWB];
  __shared__ u16 Blds[128 * ROWB];
  const int tid  = threadIdx.x;
  const int lane = tid & 63;
  const int wid  = tid >> 6;
  const int wr   = wid >> 1, wc = wid & 1;
  const int lrow = lane & 15, lhi = lane >> 4;
  const int m0 = blockIdx.x * 128;
  const int n0 = blockIdx.y * 128;
  const int arow = tid & 127;
  int m = m0 + arow;
  if (m >= M_TOT) m = M_TOT - 1;
  const int nimg = m / NV;
  const int v    = m - nimg * NV;
  const int g    = valid[v];
  const int gi   = g / GWID;
  const int gj   = g - gi * GWID;
  const float* xrow = x + (size_t)nimg * NSTRIDE + (size_t)(gi * PHh) * IMW + gj * PWw;
  const int half = tid >> 7;
  const float* wrow = w + (size_t)(n0 + arow) * K_TOT;
  f32x4 acc[4][4];
  #pragma unroll
  for (int i = 0; i < 4; ++i)
    #pragma unroll
    for (int j = 0; j < 4; ++j)
      acc[i][j] = (f32x4){0.f, 0.f, 0.f, 0.f};
  for (int t = 0; t < 7; ++t) {
    #pragma unroll
    for (int it = 0; it < 4; ++it) {
      const int run = half + it * 2;
      const int rr  = t * 8 + run;
      const int c   = rr / PHh;
      const int p   = rr - c * PHh;
      const float* src = xrow + (size_t)c * CSTRIDE + p * IMW;
      f32x4 f0 = *(const f32x4*)(src + 0);
      f32x4 f1 = *(const f32x4*)(src + 4);
      f32x4 f2 = *(const f32x4*)(src + 8);
      u16x4 h0 = {f2bf(f0.x), f2bf(f0.y), f2bf(f0.z), f2bf(f0.w)};
      u16x4 h1 = {f2bf(f1.x), f2bf(f1.y), f2bf(f1.z), f2bf(f1.w)};
      u16x4 h2 = {f2bf(f2.x), f2bf(f2.y), f2bf(f2.z), f2bf(f2.w)};
      u16* dst = &Alds[arow * ROWB + run * 12];
      *(u16x4*)(dst + 0) = h0;
      *(u16x4*)(dst + 4) = h1;
      *(u16x4*)(dst + 8) = h2;
    }
    #pragma unroll
    for (int i = 0; i < 6; ++i) {
      const int col = half * 48 + i * 8;
      const float* src = wrow + t * 96 + col;
      f32x4 f0 = *(const f32x4*)(src + 0);
      f32x4 f1 = *(const f32x4*)(src + 4);
      u16x8 h = {f2bf(f0.x), f2bf(f0.y), f2bf(f0.z), f2bf(f0.w),
                 f2bf(f1.x), f2bf(f1.y), f2bf(f1.z), f2bf(f1.w)};
      *(u16x8*)&Blds[arow * ROWB + col] = h;
    }
    __syncthreads();
    #pragma unroll
    for (int kk = 0; kk < 3; ++kk) {
      bf16x8 a[4], b[4];
      #pragma unroll
      for (int i = 0; i < 4; ++i)
        a[i] = *(const bf16x8*)&Alds[(wr * 64 + i * 16 + lrow) * ROWB + kk * 32 + lhi * 8];
      #pragma unroll
      for (int j = 0; j < 4; ++j)
        b[j] = *(const bf16x8*)&Blds[(wc * 64 + j * 16 + lrow) * ROWB + kk * 32 + lhi * 8];
      #pragma unroll
      for (int i = 0; i < 4; ++i)
        #pragma unroll
        for (int j = 0; j < 4; ++j)
          acc[i][j] = __builtin_amdgcn_mfma_f32_16x16x32_bf16(a[i], b[j], acc[i][j], 0, 0, 0);
    }
    __syncthreads();
  }
  float bv[4];
  #pragma unroll
  for (int j = 0; j < 4; ++j)
    bv[j] = bias[n0 + wc * 64 + j * 16 + lrow];
  #pragma unroll
  for (int i = 0; i < 4; ++i) {
    const int mbase = m0 + wr * 64 + i * 16 + lhi * 4;
    #pragma unroll
    for (int j = 0; j < 4; ++j) {
      const int e = n0 + wc * 64 + j * 16 + lrow;
      float* op = out + (size_t)mbase * N_E + e;
      #pragma unroll
      for (int tt = 0; tt < 4; ++tt) {
        if (mbase + tt < M_TOT) op[(size_t)tt * N_E] = acc[i][j][tt] + bv[j];
      }
    }
  }
}

extern "C" void kernel_launch(void* const* d_in, const int* in_sizes, int n_in,
                              void* d_out, int out_size, void* d_ws, size_t ws_size,
                              hipStream_t stream) {
  const float* x     = (const float*)d_in[0];
  const float* w     = (const float*)d_in[1];
  const float* b     = (const float*)d_in[2];
  const int*   valid = (const int*)d_in[3];
  float* out = (float*)d_out;

  if (ws_size >= (size_t)WS_NEEDED) {
    u16* Aws = (u16*)d_ws;
    u16* Wws = (u16*)((char*)d_ws + A_WS_BYTES);
    patchify<<<NBLK_A + NBLK_W, 256, 0, stream>>>(x, w, valid, Aws, Wws);
    dim3 grid(N_E / 128, (M_TOT + 127) / 128);   // 6 x 293, n fastest
    gemm_bf16<<<grid, dim3(256), 0, stream>>>(Aws, Wws, b, out);
  } else {
    dim3 grid((M_TOT + 127) / 128, N_E / 128);
    patch_gemm_fused<<<grid, dim3(256), 0, stream>>>(x, w, b, valid, out);
  }
}